// Round 1
// baseline (80.300 us; speedup 1.0000x reference)
//
#include <hip/hip_runtime.h>

// RFFT over non-overlapping 8x8 blocks of a (32,1,1024,1024) fp32 image,
// 1-D rFFT along the last dim of each block, output (32,16384,8,5,2) fp32
// scaled by 1/64.
//
// One thread per 8-float row. Row id t enumerates (n, bi, r) with r innermost:
//   n  = t >> 17          (16384 blocks * 8 rows = 2^17 rows per image)
//   bi = (t & 131071) >> 3, r = t & 7, bh = bi >> 7, bw = bi & 127
// Input  addr: n*2^20 + (bh*8+r)*1024 + bw*8   -> two float4 loads, 32B/lane;
//   lanes with equal r are contiguous (8 x 256B segments per wave).
// Output addr: t*10 floats -> wave writes one dense 2560B span (5 x float2).

__global__ __launch_bounds__(256) void rfft8_rows_kernel(
    const float* __restrict__ x, float* __restrict__ out, unsigned total_rows) {
    const float S = 0.70710678118654752f;  // sqrt(2)/2
    const float K = 0.015625f;             // 1/64
    const unsigned stride = gridDim.x * blockDim.x;
    for (unsigned t = blockIdx.x * blockDim.x + threadIdx.x; t < total_rows;
         t += stride) {
        const unsigned n   = t >> 17;
        const unsigned rem = t & 131071u;
        const unsigned bi  = rem >> 3;
        const unsigned r   = rem & 7u;
        const unsigned bh  = bi >> 7;
        const unsigned bw  = bi & 127u;

        const float4* in4 = reinterpret_cast<const float4*>(
            x + ((size_t)n << 20) + (size_t)(((bh << 3) + r) << 10) + (bw << 3));
        const float4 lo = in4[0];
        const float4 hi = in4[1];
        const float x0 = lo.x, x1 = lo.y, x2 = lo.z, x3 = lo.w;
        const float x4 = hi.x, x5 = hi.y, x6 = hi.z, x7 = hi.w;

        // radix-8 rFFT butterflies (numpy convention: e^{-2*pi*i*j*k/8})
        const float a04 = x0 + x4, s04 = x0 - x4;
        const float a15 = x1 + x5, s15 = x1 - x5;
        const float a26 = x2 + x6, s26 = x2 - x6;
        const float a37 = x3 + x7, s37 = x3 - x7;
        const float e = a04 + a26, f = a15 + a37;
        const float c0r = e + f;          // k=0 (imag 0)
        const float c4r = e - f;          // k=4 (imag 0)
        const float c2r = a04 - a26;      // k=2
        const float c2i = a37 - a15;
        const float sm = S * (s15 - s37);
        const float sp = S * (s15 + s37);
        const float c1r = s04 + sm;       // k=1
        const float c1i = -s26 - sp;
        const float c3r = s04 - sm;       // k=3
        const float c3i = s26 - sp;

        float2* o2 = reinterpret_cast<float2*>(out + (size_t)t * 10u);
        o2[0] = make_float2(c0r * K, 0.0f);
        o2[1] = make_float2(c1r * K, c1i * K);
        o2[2] = make_float2(c2r * K, c2i * K);
        o2[3] = make_float2(c3r * K, c3i * K);
        o2[4] = make_float2(c4r * K, 0.0f);
    }
}

extern "C" void kernel_launch(void* const* d_in, const int* in_sizes, int n_in,
                              void* d_out, int out_size, void* d_ws, size_t ws_size,
                              hipStream_t stream) {
    const float* x = (const float*)d_in[0];
    float* out = (float*)d_out;
    const unsigned total_rows = (unsigned)((size_t)in_sizes[0] >> 3);  // 4194304
    const int block = 256;
    const int grid = 2048;  // grid-stride: 8 rows per thread
    hipLaunchKernelGGL(rfft8_rows_kernel, dim3(grid), dim3(block), 0, stream,
                       x, out, total_rows);
}

// Round 2
// 53.479 us; speedup vs baseline: 1.5015x; 1.5015x over previous
//
#include <hip/hip_runtime.h>

// RFFT over non-overlapping 8x8 blocks of a (32,1,1024,1024) fp32 image,
// 1-D rFFT along the last dim of each block row, output (32,16384,8,5,2) fp32
// scaled by 1/64.
//
// One thread per 8-float row, t in OUTPUT order:
//   n = t>>17, bi = (t&131071)>>3, r = t&7, bh = bi>>7, bw = bi&127
// Reads: two float4 per lane; the wave's 64 lanes form 8 rows x 256B
// contiguous segments (lines fully consumed across the 2 load instrs).
// Writes: staged through LDS so every global store instruction is a dense
// lane-contiguous span (each 256-thread block emits 2560 consecutive floats
// as 2x float4 + 1x float2 per thread).

__global__ __launch_bounds__(256) void rfft8_rows_kernel(
    const float* __restrict__ x, float* __restrict__ out, unsigned total_rows) {
    const float S = 0.70710678118654752f;  // sqrt(2)/2
    const float K = 0.015625f;             // 1/64
    __shared__ float lds[2560];
    const unsigned tid = threadIdx.x;

    for (unsigned B = blockIdx.x; B * 256u < total_rows; B += gridDim.x) {
        const unsigned t = B * 256u + tid;
        const unsigned n   = t >> 17;
        const unsigned rem = t & 131071u;
        const unsigned bi  = rem >> 3;
        const unsigned r   = rem & 7u;
        const unsigned bh  = bi >> 7;
        const unsigned bw  = bi & 127u;

        const float4* in4 = reinterpret_cast<const float4*>(
            x + ((size_t)n << 20) + (size_t)(((bh << 3) + r) << 10) + (bw << 3));
        const float4 lo = in4[0];
        const float4 hi = in4[1];
        const float x0 = lo.x, x1 = lo.y, x2 = lo.z, x3 = lo.w;
        const float x4 = hi.x, x5 = hi.y, x6 = hi.z, x7 = hi.w;

        // radix-8 rFFT butterflies (numpy convention: e^{-2*pi*i*j*k/8})
        const float a04 = x0 + x4, s04 = x0 - x4;
        const float a15 = x1 + x5, s15 = x1 - x5;
        const float a26 = x2 + x6, s26 = x2 - x6;
        const float a37 = x3 + x7, s37 = x3 - x7;
        const float e = a04 + a26, f = a15 + a37;
        const float c0r = e + f;          // k=0 (imag 0)
        const float c4r = e - f;          // k=4 (imag 0)
        const float c2r = a04 - a26;      // k=2
        const float c2i = a37 - a15;
        const float sm = S * (s15 - s37);
        const float sp = S * (s15 + s37);
        const float c1r = s04 + sm;       // k=1
        const float c1i = -s26 - sp;
        const float c3r = s04 - sm;       // k=3
        const float c3i = s26 - sp;

        // Stage this row's 10 outputs at lds[tid*10 .. tid*10+9].
        float2* l2 = reinterpret_cast<float2*>(lds + tid * 10u);
        l2[0] = make_float2(c0r * K, 0.0f);
        l2[1] = make_float2(c1r * K, c1i * K);
        l2[2] = make_float2(c2r * K, c2i * K);
        l2[3] = make_float2(c3r * K, c3i * K);
        l2[4] = make_float2(c4r * K, 0.0f);
        __syncthreads();

        // Dense block write: 2560 consecutive floats at out + B*2560.
        float* ob = out + (size_t)B * 2560u;
        const float4* l4 = reinterpret_cast<const float4*>(lds);
        float4* o4 = reinterpret_cast<float4*>(ob);
        o4[tid]        = l4[tid];
        o4[tid + 256u] = l4[tid + 256u];
        reinterpret_cast<float2*>(ob)[1024u + tid] =
            reinterpret_cast<const float2*>(lds)[1024u + tid];
        __syncthreads();  // protect lds before next iteration's staging
    }
}

extern "C" void kernel_launch(void* const* d_in, const int* in_sizes, int n_in,
                              void* d_out, int out_size, void* d_ws, size_t ws_size,
                              hipStream_t stream) {
    const float* x = (const float*)d_in[0];
    float* out = (float*)d_out;
    const unsigned total_rows = (unsigned)((size_t)in_sizes[0] >> 3);  // 4194304
    const int block = 256;
    const int grid = 2048;  // grid-stride: 8 block-iterations per CU-slot
    hipLaunchKernelGGL(rfft8_rows_kernel, dim3(grid), dim3(block), 0, stream,
                       x, out, total_rows);
}

// Round 4
// 49.950 us; speedup vs baseline: 1.6076x; 1.0706x over previous
//
#include <hip/hip_runtime.h>

// RFFT over non-overlapping 8x8 blocks of a (32,1,1024,1024) fp32 image,
// 1-D rFFT along the last dim of each block row, output (32,16384,8,5,2) fp32
// scaled by 1/64.
//
// One thread per 8-float row, t in OUTPUT order:
//   n = t>>17, bi = (t&131071)>>3, r = t&7, bh = bi>>7, bw = bi&127
// Reads: two float4 per lane; a wave's loads form 8 x 256B segments whose
// 64B sectors are fully consumed across the adjacent load pair.
// Writes: staged through double-buffered LDS (one barrier per iteration),
// then stored as dense lane-contiguous nontemporal float4/float2 spans
// (2560 consecutive floats per 256-thread block).

typedef float f32x4 __attribute__((ext_vector_type(4)));
typedef float f32x2 __attribute__((ext_vector_type(2)));

__global__ __launch_bounds__(256) void rfft8_rows_kernel(
    const float* __restrict__ x, float* __restrict__ out, unsigned total_rows) {
    const float S = 0.70710678118654752f;  // sqrt(2)/2
    const float K = 0.015625f;             // 1/64
    __shared__ float lds[2][2560];
    const unsigned tid = threadIdx.x;

    unsigned buf = 0;
    for (unsigned B = blockIdx.x; B * 256u < total_rows; B += gridDim.x, buf ^= 1u) {
        const unsigned t = B * 256u + tid;
        const unsigned n   = t >> 17;
        const unsigned rem = t & 131071u;
        const unsigned bi  = rem >> 3;
        const unsigned r   = rem & 7u;
        const unsigned bh  = bi >> 7;
        const unsigned bw  = bi & 127u;

        const f32x4* in4 = reinterpret_cast<const f32x4*>(
            x + ((size_t)n << 20) + (size_t)(((bh << 3) + r) << 10) + (bw << 3));
        const f32x4 lo = in4[0];
        const f32x4 hi = in4[1];
        const float x0 = lo.x, x1 = lo.y, x2 = lo.z, x3 = lo.w;
        const float x4 = hi.x, x5 = hi.y, x6 = hi.z, x7 = hi.w;

        // radix-8 rFFT butterflies (numpy convention: e^{-2*pi*i*j*k/8})
        const float a04 = x0 + x4, s04 = x0 - x4;
        const float a15 = x1 + x5, s15 = x1 - x5;
        const float a26 = x2 + x6, s26 = x2 - x6;
        const float a37 = x3 + x7, s37 = x3 - x7;
        const float e = a04 + a26, f = a15 + a37;
        const float c0r = e + f;          // k=0 (imag 0)
        const float c4r = e - f;          // k=4 (imag 0)
        const float c2r = a04 - a26;      // k=2
        const float c2i = a37 - a15;
        const float sm = S * (s15 - s37);
        const float sp = S * (s15 + s37);
        const float c1r = s04 + sm;       // k=1
        const float c1i = -s26 - sp;
        const float c3r = s04 - sm;       // k=3
        const float c3i = s26 - sp;

        // Stage this row's 10 outputs at lds[buf][tid*10 .. tid*10+9].
        float* lb = lds[buf];
        f32x2* l2 = reinterpret_cast<f32x2*>(lb + tid * 10u);
        l2[0] = (f32x2){c0r * K, 0.0f};
        l2[1] = (f32x2){c1r * K, c1i * K};
        l2[2] = (f32x2){c2r * K, c2i * K};
        l2[3] = (f32x2){c3r * K, c3i * K};
        l2[4] = (f32x2){c4r * K, 0.0f};
        __syncthreads();

        // Dense block write: 2560 consecutive floats at out + B*2560.
        // Streaming output (never re-read) -> nontemporal stores.
        float* ob = out + (size_t)B * 2560u;
        const f32x4* l4 = reinterpret_cast<const f32x4*>(lb);
        f32x4* o4 = reinterpret_cast<f32x4*>(ob);
        __builtin_nontemporal_store(l4[tid], o4 + tid);
        __builtin_nontemporal_store(l4[tid + 256u], o4 + tid + 256u);
        __builtin_nontemporal_store(reinterpret_cast<const f32x2*>(lb)[1024u + tid],
                                    reinterpret_cast<f32x2*>(ob) + 1024u + tid);
        // No trailing barrier: next iteration stages into the other buffer;
        // the following iteration's barrier orders reuse of this one.
    }
}

extern "C" void kernel_launch(void* const* d_in, const int* in_sizes, int n_in,
                              void* d_out, int out_size, void* d_ws, size_t ws_size,
                              hipStream_t stream) {
    const float* x = (const float*)d_in[0];
    float* out = (float*)d_out;
    const unsigned total_rows = (unsigned)((size_t)in_sizes[0] >> 3);  // 4194304
    const int block = 256;
    const int grid = 2048;  // 8 block-iterations per slot; 8 blocks/CU resident
    hipLaunchKernelGGL(rfft8_rows_kernel, dim3(grid), dim3(block), 0, stream,
                       x, out, total_rows);
}